// Round 14
// baseline (1315.538 us; speedup 1.0000x reference)
//
#include <hip/hip_runtime.h>
#include <math.h>

#define VOCAB   50000
#define EMBED   256
#define HIDDEN  64
#define G4      256     // 4*HIDDEN
#define BATCH   64
#define TSEQ    2048
#define NUM_OUT 16

typedef _Float16 h2    __attribute__((ext_vector_type(2)));
typedef _Float16 f16x8 __attribute__((ext_vector_type(8)));
typedef float    f32x4 __attribute__((ext_vector_type(4)));

#define LOG2E  1.4426950408889634f
#define LOG2E2 2.8853900817779268f

__device__ __forceinline__ float fexp2f(float x) { return __builtin_amdgcn_exp2f(x); }
__device__ __forceinline__ float frcpf(float x)  { return __builtin_amdgcn_rcpf(x); }

// f16x2 dot with fp32 accumulate — v_dot2_f32_f16
__device__ __forceinline__ float dot2(h2 a, h2 b, float c) {
#if __has_builtin(__builtin_amdgcn_fdot2)
    return __builtin_amdgcn_fdot2(a, b, c, false);
#else
    float r;
    asm("v_dot2_f32_f16 %0, %1, %2, %3"
        : "=v"(r)
        : "v"(__builtin_bit_cast(int, a)), "v"(__builtin_bit_cast(int, b)), "v"(c));
    return r;
#endif
}

// xor-1 neighbor exchange as pure-VALU DPP (quad_perm [1,0,3,2] = 0xB1)
__device__ __forceinline__ int dpp_xor1(int v) {
    return __builtin_amdgcn_update_dpp(0, v, 0xB1, 0xF, 0xF, true);
}
// pack (h_self, h_neighbor) -> f16x2 dword; valid in even lanes
__device__ __forceinline__ int pkpair(float h) {
    int hp = dpp_xor1(__float_as_int(h));
    return __builtin_bit_cast(int,
        __builtin_amdgcn_cvt_pkrtz(h, __int_as_float(hp)));
}
__device__ __forceinline__ h2 bch2(int v) { return __builtin_bit_cast(h2, v); }

// W_ih pre-converted to f16 (bits), [gate][k] row-major. 128 KB static.
__device__ __align__(16) short g_Wf16[G4 * EMBED];

__global__ __launch_bounds__(256) void wcvt_kernel(const float* __restrict__ W_ih) {
    int i = (blockIdx.x * 256 + threadIdx.x) * 4;
    float4 v = *(const float4*)&W_ih[i];
    short4 o;
    o.x = __builtin_bit_cast(short, (_Float16)v.x);
    o.y = __builtin_bit_cast(short, (_Float16)v.y);
    o.z = __builtin_bit_cast(short, (_Float16)v.z);
    o.w = __builtin_bit_cast(short, (_Float16)v.w);
    *(short4*)&g_Wf16[i] = o;
}

// ---------------------------------------------------------------------------
// proj via MFMA f16 (R12 compute). STORE LAYOUT: unit-major —
// proj[tok][unit*4 + q], q = gate (i,f,g,o), value pre-scaled by
// log2e (2*log2e for gate g). Scan lane j reads one coalesced float4.
// ---------------------------------------------------------------------------
__global__ __launch_bounds__(256) void proj_mfma(
    const float* __restrict__ emb,
    const float* __restrict__ b_ih, const float* __restrict__ b_hh,
    float* __restrict__ proj)
{
    __shared__ __align__(16) short As[64][264];   // f16 emb tile, +8 pad

    const int tid  = threadIdx.x;
    const int w    = tid >> 6;
    const int lane = tid & 63;
    const int R0   = blockIdx.x * 64;

    #pragma unroll
    for (int it = 0; it < 16; ++it) {
        int flat = it * 256 + tid;
        int r  = flat >> 6;
        int c4 = flat & 63;
        int row = R0 + r; row = row < VOCAB ? row : VOCAB - 1;
        float4 v = *(const float4*)&emb[(size_t)row * EMBED + c4 * 4];
        short4 o;
        o.x = __builtin_bit_cast(short, (_Float16)v.x);
        o.y = __builtin_bit_cast(short, (_Float16)v.y);
        o.z = __builtin_bit_cast(short, (_Float16)v.z);
        o.w = __builtin_bit_cast(short, (_Float16)v.w);
        *(short4*)&As[r][c4 * 4] = o;
    }
    __syncthreads();

    f32x4 acc[16];
    #pragma unroll
    for (int t = 0; t < 16; ++t) acc[t] = f32x4{0.f, 0.f, 0.f, 0.f};

    const short* arow = &As[w * 16 + (lane & 15)][(lane >> 4) * 8];
    const int boff = (lane & 15) * EMBED + (lane >> 4) * 8;

    #pragma unroll
    for (int kc = 0; kc < 8; ++kc) {
        f16x8 af = *(const f16x8*)(arow + kc * 32);
        #pragma unroll
        for (int t = 0; t < 16; ++t) {
            f16x8 bf = *(const f16x8*)&g_Wf16[t * 16 * EMBED + kc * 32 + boff];
            acc[t] = __builtin_amdgcn_mfma_f32_16x16x32_f16(af, bf, acc[t], 0, 0, 0);
        }
    }

    // tile t covers gate g = 16t + colin: q = t>>2, unit = (t&3)*16 + colin.
    // store unit-major float4 per unit: component q <- tile t = q*4 + ug.
    const int crow0 = R0 + w * 16 + (lane >> 4) * 4;
    const int colin = lane & 15;

    float bs[4][4];   // [q][ug]
    #pragma unroll
    for (int q = 0; q < 4; ++q)
        #pragma unroll
        for (int ug = 0; ug < 4; ++ug) {
            int gidx = q * 64 + ug * 16 + colin;
            bs[q][ug] = b_ih[gidx] + b_hh[gidx];
        }

    #pragma unroll
    for (int j = 0; j < 4; ++j) {
        int row = crow0 + j;
        if (row < VOCAB) {
            #pragma unroll
            for (int ug = 0; ug < 4; ++ug) {
                float4 o;
                o.x = (acc[0 * 4 + ug][j] + bs[0][ug]) * LOG2E;
                o.y = (acc[1 * 4 + ug][j] + bs[1][ug]) * LOG2E;
                o.z = (acc[2 * 4 + ug][j] + bs[2][ug]) * LOG2E2;
                o.w = (acc[3 * 4 + ug][j] + bs[3][ug]) * LOG2E;
                *(float4*)&proj[(size_t)row * G4 + (ug * 16 + colin) * 4] = o;
            }
        }
    }
}

// ---------------------------------------------------------------------------
// SINGLE-WAVE LSTM scan, weights in LDS — no barrier, no cross-wave handoff,
// no register-resident weight array (kills the R2-R7 allocator phantom).
// Lane j owns unit j (all 4 gates). Per step: 8 broadcast ds_read_b128 (h),
// 32 ds_read_b128 (weights, stride-16B contiguous = conflict-free), 128 dot2.
// Anti-hoist asm on the weight offset stops cross-step CSE of the reads
// (they are loop-invariant; hoisting = 128 live VGPRs = phantom again).
// h redistribution: dpp+cvt_pk -> 32 ds_write_b32 -> in-order DS pipe.
// ---------------------------------------------------------------------------
__global__ __launch_bounds__(64) void lstm_scan(
    const int* __restrict__ x, const float* __restrict__ proj,
    const float* __restrict__ W_hh,
    const float* __restrict__ bn_gamma, const float* __restrict__ bn_beta,
    const float* __restrict__ bn_mean, const float* __restrict__ bn_var,
    const float* __restrict__ fc_w, const float* __restrict__ fc_b,
    float* __restrict__ out)
{
    const int b = blockIdx.x;
    const int j = threadIdx.x;   // 0..63, hidden unit index

    __shared__ int   toks[TSEQ + 8];
    __shared__ __align__(16) short wlds[32 * 64 * 8];  // 32 KB: slot(m*4+q), lane j
    __shared__ __align__(16) int   hx[32];             // packed f16 h pairs
    __shared__ float hb_s[HIDDEN];

    for (int i = j; i < TSEQ + 8; i += 64)
        toks[i] = x[b * TSEQ + (i < TSEQ ? i : TSEQ - 1)];
    if (j < 32) hx[j] = 0;       // h(-1) = 0

    // stage pre-scaled f16 weights: slot s = m*4+q holds W_hh[q*64+j][8m..8m+8]
    #pragma unroll
    for (int q = 0; q < 4; ++q) {
        const float* wr = W_hh + (size_t)(q * HIDDEN + j) * HIDDEN;
        const float sck = (q == 2) ? LOG2E2 : LOG2E;
        #pragma unroll
        for (int m = 0; m < 8; ++m) {
            float4 lo = *(const float4*)(wr + m * 8);
            float4 hi = *(const float4*)(wr + m * 8 + 4);
            int4 o;
            o.x = __builtin_bit_cast(int, h2{(_Float16)(lo.x * sck), (_Float16)(lo.y * sck)});
            o.y = __builtin_bit_cast(int, h2{(_Float16)(lo.z * sck), (_Float16)(lo.w * sck)});
            o.z = __builtin_bit_cast(int, h2{(_Float16)(hi.x * sck), (_Float16)(hi.y * sck)});
            o.w = __builtin_bit_cast(int, h2{(_Float16)(hi.z * sck), (_Float16)(hi.w * sck)});
            *(int4*)&wlds[((m * 4 + q) * 64 + j) * 8] = o;
        }
    }
    __syncthreads();   // single wave: cheap; orders staging vs loop

    float cc = 0.0f, hmy = 0.0f;          // cc = 2*log2e * c_true (scaled)
    const float* projc = proj + j * 4;    // lane's gx float4 column

    // depth-4 gx prefetch
    float4 gx0 = *(const float4*)(projc + (size_t)toks[0] * G4);
    float4 gx1 = *(const float4*)(projc + (size_t)toks[1] * G4);
    float4 gx2 = *(const float4*)(projc + (size_t)toks[2] * G4);
    float4 gx3 = *(const float4*)(projc + (size_t)toks[3] * G4);
    int tk0 = toks[4], tk1 = toks[5], tk2 = toks[6], tk3 = toks[7];

#define GRP(m, R) { \
    int4 w0 = wpj[((m) * 4 + 0) * 64]; \
    int4 w1 = wpj[((m) * 4 + 1) * 64]; \
    int4 w2 = wpj[((m) * 4 + 2) * 64]; \
    int4 w3 = wpj[((m) * 4 + 3) * 64]; \
    ai = dot2(bch2(w0.x), bch2(R.x), ai); ai = dot2(bch2(w0.y), bch2(R.y), ai); \
    ai = dot2(bch2(w0.z), bch2(R.z), ai); ai = dot2(bch2(w0.w), bch2(R.w), ai); \
    af = dot2(bch2(w1.x), bch2(R.x), af); af = dot2(bch2(w1.y), bch2(R.y), af); \
    af = dot2(bch2(w1.z), bch2(R.z), af); af = dot2(bch2(w1.w), bch2(R.w), af); \
    ag = dot2(bch2(w2.x), bch2(R.x), ag); ag = dot2(bch2(w2.y), bch2(R.y), ag); \
    ag = dot2(bch2(w2.z), bch2(R.z), ag); ag = dot2(bch2(w2.w), bch2(R.w), ag); \
    ao = dot2(bch2(w3.x), bch2(R.x), ao); ao = dot2(bch2(w3.y), bch2(R.y), ao); \
    ao = dot2(bch2(w3.z), bch2(R.z), ao); ao = dot2(bch2(w3.w), bch2(R.w), ao); \
}

#define STEP(GX, TK, TT) { \
    /* chain head: broadcast h reads (all lanes same address) */ \
    const int4* hp4 = (const int4*)hx; \
    int4 r0 = hp4[0], r1 = hp4[1], r2 = hp4[2], r3 = hp4[3]; \
    int4 r4 = hp4[4], r5 = hp4[5], r6 = hp4[6], r7 = hp4[7]; \
    /* anti-hoist: weight reads must not be CSE'd across steps */ \
    int woff = 0; \
    asm volatile("" : "+v"(woff)); \
    const int4* wpj = (const int4*)((const char*)wlds + woff) + j; \
    int tnew = toks[(TT) + 8]; \
    float4 gnew = *(const float4*)(projc + (size_t)(TK) * G4); \
    float ai = GX.x, af = GX.y, ag = GX.z, ao = GX.w; \
    GRP(0, r0) GRP(1, r1) GRP(2, r2) GRP(3, r3) \
    GRP(4, r4) GRP(5, r5) GRP(6, r6) GRP(7, r7) \
    GX = gnew; TK = tnew; \
    float i_ = 1.0f - frcpf(fexp2f(ai) + 1.0f); \
    float f_ = 1.0f - frcpf(fexp2f(af) + 1.0f); \
    float g_ = fmaf(-2.0f * LOG2E2, frcpf(fexp2f(ag) + 1.0f), LOG2E2); \
    float o_ = 1.0f - frcpf(fexp2f(ao) + 1.0f); \
    cc = fmaf(f_, cc, i_ * g_); \
    float rv2 = frcpf(fexp2f(cc) + 1.0f); \
    hmy = fmaf(-(o_ + o_), rv2, o_); \
    int pk = pkpair(hmy); \
    if ((j & 1) == 0) hx[j >> 1] = pk; \
}

    for (int t = 0; t < TSEQ; t += 4) {
        STEP(gx0, tk0, t)
        STEP(gx1, tk1, t + 1)
        STEP(gx2, tk2, t + 2)
        STEP(gx3, tk3, t + 3)
    }
#undef STEP
#undef GRP

    // epilogue: BN then FC (lane j owns h_j)
    float hb = (hmy - bn_mean[j]) * rsqrtf(bn_var[j] + 1e-5f) * bn_gamma[j]
               + bn_beta[j];
    hb_s[j] = hb;
    __syncthreads();
    if (j < NUM_OUT) {
        float s0 = fc_b[j], s1 = 0.f, s2 = 0.f, s3 = 0.f;
        #pragma unroll
        for (int k = 0; k < HIDDEN; k += 4) {
            s0 = fmaf(hb_s[k + 0], fc_w[j * HIDDEN + k + 0], s0);
            s1 = fmaf(hb_s[k + 1], fc_w[j * HIDDEN + k + 1], s1);
            s2 = fmaf(hb_s[k + 2], fc_w[j * HIDDEN + k + 2], s2);
            s3 = fmaf(hb_s[k + 3], fc_w[j * HIDDEN + k + 3], s3);
        }
        out[b * NUM_OUT + j] = (s0 + s1) + (s2 + s3);
    }
}

// ---------------------------------------------------------------------------
extern "C" void kernel_launch(void* const* d_in, const int* in_sizes, int n_in,
                              void* d_out, int out_size, void* d_ws, size_t ws_size,
                              hipStream_t stream) {
    const int*   x        = (const int*)d_in[0];
    // d_in[1] = seq_lengths: unused by the reference computation
    const float* emb      = (const float*)d_in[2];
    const float* W_ih     = (const float*)d_in[3];
    const float* W_hh     = (const float*)d_in[4];
    const float* b_ih     = (const float*)d_in[5];
    const float* b_hh     = (const float*)d_in[6];
    const float* bn_gamma = (const float*)d_in[7];
    const float* bn_beta  = (const float*)d_in[8];
    const float* bn_mean  = (const float*)d_in[9];
    const float* bn_var   = (const float*)d_in[10];
    const float* fc_w     = (const float*)d_in[11];
    const float* fc_b     = (const float*)d_in[12];

    float* proj = (float*)d_ws;  // VOCAB * 256 * 4 B = 51.2 MB

    wcvt_kernel<<<G4 * EMBED / (256 * 4), 256, 0, stream>>>(W_ih);
    proj_mfma<<<(VOCAB + 63) / 64, 256, 0, stream>>>(emb, b_ih, b_hh, proj);

    lstm_scan<<<BATCH, 64, 0, stream>>>(x, proj, W_hh,
                                        bn_gamma, bn_beta, bn_mean, bn_var,
                                        fc_w, fc_b, (float*)d_out);
}

// Round 16
// 642.142 us; speedup vs baseline: 2.0487x; 2.0487x over previous
//
#include <hip/hip_runtime.h>
#include <math.h>

#define VOCAB   50000
#define EMBED   256
#define HIDDEN  64
#define G4      256     // 4*HIDDEN
#define BATCH   64
#define TSEQ    2048
#define NUM_OUT 16

typedef _Float16 h2    __attribute__((ext_vector_type(2)));
typedef _Float16 f16x8 __attribute__((ext_vector_type(8)));
typedef float    f32x4 __attribute__((ext_vector_type(4)));

#define LOG2E  1.4426950408889634f
#define LOG2E2 2.8853900817779268f

__device__ __forceinline__ float fexp2f(float x) { return __builtin_amdgcn_exp2f(x); }
__device__ __forceinline__ float frcpf(float x)  { return __builtin_amdgcn_rcpf(x); }

// f16x2 dot with fp32 accumulate — v_dot2_f32_f16
__device__ __forceinline__ float dot2(h2 a, h2 b, float c) {
#if __has_builtin(__builtin_amdgcn_fdot2)
    return __builtin_amdgcn_fdot2(a, b, c, false);
#else
    float r;
    asm("v_dot2_f32_f16 %0, %1, %2, %3"
        : "=v"(r)
        : "v"(__builtin_bit_cast(int, a)), "v"(__builtin_bit_cast(int, b)), "v"(c));
    return r;
#endif
}

// quad_perm DPP: pure-VALU intra-quad exchange
template <int CTRL>
__device__ __forceinline__ float dppf(float v) {
    return __int_as_float(__builtin_amdgcn_update_dpp(
        0, __float_as_int(v), CTRL, 0xF, 0xF, true));
}

#define REP32(M) M(0) M(1) M(2) M(3) M(4) M(5) M(6) M(7) \
                 M(8) M(9) M(10) M(11) M(12) M(13) M(14) M(15) \
                 M(16) M(17) M(18) M(19) M(20) M(21) M(22) M(23) \
                 M(24) M(25) M(26) M(27) M(28) M(29) M(30) M(31)

// W_ih pre-converted to f16 (bits), [gate][k] row-major. 128 KB static.
__device__ __align__(16) short g_Wf16[G4 * EMBED];

__global__ __launch_bounds__(256) void wcvt_kernel(const float* __restrict__ W_ih) {
    int i = (blockIdx.x * 256 + threadIdx.x) * 4;   // 64 blocks cover 65536
    float4 v = *(const float4*)&W_ih[i];
    short4 o;
    o.x = __builtin_bit_cast(short, (_Float16)v.x);
    o.y = __builtin_bit_cast(short, (_Float16)v.y);
    o.z = __builtin_bit_cast(short, (_Float16)v.z);
    o.w = __builtin_bit_cast(short, (_Float16)v.w);
    *(short4*)&g_Wf16[i] = o;
}

// ---------------------------------------------------------------------------
// proj via MFMA f16: B-fragments from pre-converted g_Wf16 (L2-resident,
// direct dwordx4, no per-block conversion); A staged through LDS (coalesced
// float4 global reads -> f16 LDS, 16B row pad -> 2-way-conflict b128 reads).
// proj[v][g] = (dot(emb[v],W_ih[g]) + b_ih[g] + b_hh[g]) * s_gate.
// C/D layout (verified m89): col=lane&15, row=(lane>>4)*4+j.
// ---------------------------------------------------------------------------
__global__ __launch_bounds__(256) void proj_mfma(
    const float* __restrict__ emb,
    const float* __restrict__ b_ih, const float* __restrict__ b_hh,
    float* __restrict__ proj)
{
    __shared__ __align__(16) short As[64][264];   // f16 emb tile, +8 pad

    const int tid  = threadIdx.x;
    const int w    = tid >> 6;
    const int lane = tid & 63;
    const int R0   = blockIdx.x * 64;

    // stage 64 emb rows -> f16 LDS (coalesced float4 reads)
    #pragma unroll
    for (int it = 0; it < 16; ++it) {
        int flat = it * 256 + tid;        // 0..4095 float4s
        int r  = flat >> 6;               // 0..63
        int c4 = flat & 63;               // float4 index within row
        int row = R0 + r; row = row < VOCAB ? row : VOCAB - 1;
        float4 v = *(const float4*)&emb[(size_t)row * EMBED + c4 * 4];
        short4 o;
        o.x = __builtin_bit_cast(short, (_Float16)v.x);
        o.y = __builtin_bit_cast(short, (_Float16)v.y);
        o.z = __builtin_bit_cast(short, (_Float16)v.z);
        o.w = __builtin_bit_cast(short, (_Float16)v.w);
        *(short4*)&As[r][c4 * 4] = o;
    }
    __syncthreads();

    f32x4 acc[16];
    #pragma unroll
    for (int t = 0; t < 16; ++t) acc[t] = f32x4{0.f, 0.f, 0.f, 0.f};

    const short* arow = &As[w * 16 + (lane & 15)][(lane >> 4) * 8];
    const int boff = (lane & 15) * EMBED + (lane >> 4) * 8;

    #pragma unroll
    for (int kc = 0; kc < 8; ++kc) {
        f16x8 af = *(const f16x8*)(arow + kc * 32);
        #pragma unroll
        for (int t = 0; t < 16; ++t) {
            f16x8 bf = *(const f16x8*)&g_Wf16[t * 16 * EMBED + kc * 32 + boff];
            acc[t] = __builtin_amdgcn_mfma_f32_16x16x32_f16(af, bf, acc[t], 0, 0, 0);
        }
    }

    const int crow0 = R0 + w * 16 + (lane >> 4) * 4;
    const int colin = lane & 15;
    #pragma unroll
    for (int t = 0; t < 16; ++t) {
        int g = t * 16 + colin;
        float bias = b_ih[g] + b_hh[g];
        float sc = ((t >> 2) == 2) ? LOG2E2 : LOG2E;
        #pragma unroll
        for (int j = 0; j < 4; ++j) {
            int row = crow0 + j;
            if (row < VOCAB)
                proj[(size_t)row * G4 + g] = (acc[t][j] + bias) * sc;
        }
    }
}

// ---------------------------------------------------------------------------
// 4-wave LSTM scan, quad-local gates (R11/R12, verified 574 us — the
// structural latency floor of this recurrence on MI355X):
//  - lane l = gate q (l&3) of unit 16w+(l>>2); gate combine = 3 quad_perm
//    DPPs + cndmask (pure VALU, no LDS)
//  - proj & W_hh pre-scaled by log2e (2*log2e for g) -> exp2 direct
//  - cell state carried SCALED (c' = 2*log2e*c) -> tanh(c) with no mul
//  - only h crosses waves: f16 ds_write_b16 (q==0), ONE s_barrier, 8x
//    broadcast ds_read_b128; double-buffered; fence closes hoist race
//  - depth-4 gx prefetch, fixed register roles; toks padded
// Per-step chain ~650 cyc = read 120 + dots 80 + act/update 80 + handoff
// ~300 + sched. Five structural alternatives (1-wave reg/LDS/AGPR/MFMA,
// 8-wave SMT) all measured worse — see session journal R2-R15.
// ---------------------------------------------------------------------------
__global__ __launch_bounds__(256) void lstm_scan(
    const int* __restrict__ x, const float* __restrict__ proj,
    const float* __restrict__ W_hh,
    const float* __restrict__ bn_gamma, const float* __restrict__ bn_beta,
    const float* __restrict__ bn_mean, const float* __restrict__ bn_var,
    const float* __restrict__ fc_w, const float* __restrict__ fc_b,
    float* __restrict__ out)
{
    const int b   = blockIdx.x;
    const int tid = threadIdx.x;
    const int w   = tid >> 6;        // wave 0..3: units 16w .. 16w+15
    const int l   = tid & 63;
    const int q   = l & 3;           // gate index (i,f,g,o)
    const int unit = w * 16 + (l >> 2);

    __shared__ int   toks[TSEQ + 8];                 // padded: no tail clamp
    __shared__ __align__(16) short hbuf[2][HIDDEN];  // f16 h, double-buffered
    __shared__ float hfin[HIDDEN];
    __shared__ float hb_s[HIDDEN];

    for (int i = tid; i < TSEQ + 8; i += 256)
        toks[i] = x[b * TSEQ + (i < TSEQ ? i : TSEQ - 1)];
    if (tid < 2 * HIDDEN) ((short*)hbuf)[tid] = 0;   // h(-1) = 0 (both bufs)

    // this lane's W_hh row (gate q, unit), pre-scaled by s_k, as f16 pairs
    const float s_k = (q == 2) ? LOG2E2 : LOG2E;
    const float* Wr = &W_hh[(size_t)(q * HIDDEN + unit) * HIDDEN];
#define WR_DECL(n) h2 wr##n;
    REP32(WR_DECL)
#undef WR_DECL
#define WR_LOAD(n) { float2 v = *(const float2*)&Wr[2 * (n)]; \
                     wr##n = h2{(_Float16)(v.x * s_k), (_Float16)(v.y * s_k)}; }
    REP32(WR_LOAD)
#undef WR_LOAD

    // act constants: sigma lanes: 1 - 1*rcp ; g lane: 2.885 - 5.771*rcp
    const float s_c = (q == 2) ? LOG2E2 : 1.0f;
    const float s_m = (q == 2) ? 2.0f * LOG2E2 : 1.0f;
    const bool qodd = (q & 1) != 0;
    const bool qhi  = (q & 2) != 0;

    float c = 0.0f, hmy = 0.0f;      // c is SCALED: c' = 2*log2e * c_true
    const float* projw = proj + q * HIDDEN + unit;   // gate-major column

    __syncthreads();

    // depth-4 gx prefetch; tokens for t+4 staged
    float gx0 = projw[(size_t)toks[0] * G4];
    float gx1 = projw[(size_t)toks[1] * G4];
    float gx2 = projw[(size_t)toks[2] * G4];
    float gx3 = projw[(size_t)toks[3] * G4];
    int tk0 = toks[4], tk1 = toks[5], tk2 = toks[6], tk3 = toks[7];

    // hoisted LDS base pointers (loop-invariant)
    const int4* hp0 = (const int4*)hbuf[0];
    const int4* hp1 = (const int4*)hbuf[1];

#define DOTG(R, W0, W1, W2, W3) \
    a0 = dot2(W0, __builtin_bit_cast(h2, R.x), a0); \
    a1 = dot2(W1, __builtin_bit_cast(h2, R.y), a1); \
    a2 = dot2(W2, __builtin_bit_cast(h2, R.z), a2); \
    a3 = dot2(W3, __builtin_bit_cast(h2, R.w), a3);

#define STEP(HP, WB, GX, TK, TT) { \
    int4 r0 = (HP)[0], r1 = (HP)[1], r2 = (HP)[2], r3 = (HP)[3]; \
    int4 r4 = (HP)[4], r5 = (HP)[5], r6 = (HP)[6], r7 = (HP)[7]; \
    int tnew = toks[(TT) + 8]; \
    float gnew = projw[(size_t)(TK) * G4]; \
    float a0 = GX, a1 = 0.f, a2 = 0.f, a3 = 0.f; \
    DOTG(r0, wr0,  wr1,  wr2,  wr3)  DOTG(r1, wr4,  wr5,  wr6,  wr7) \
    DOTG(r2, wr8,  wr9,  wr10, wr11) DOTG(r3, wr12, wr13, wr14, wr15) \
    DOTG(r4, wr16, wr17, wr18, wr19) DOTG(r5, wr20, wr21, wr22, wr23) \
    DOTG(r6, wr24, wr25, wr26, wr27) DOTG(r7, wr28, wr29, wr30, wr31) \
    float gv = (a0 + a1) + (a2 + a3); \
    GX = gnew; TK = tnew; \
    float tt2 = fexp2f(gv); \
    float rr = fmaf(-s_m, frcpf(tt2 + 1.0f), s_c);       /* act(own gate) */ \
    float b1 = dppf<0xB1>(rr);                           /* quad xor1 */ \
    float b2 = dppf<0x4E>(rr);                           /* quad xor2 */ \
    float b3 = dppf<0x1B>(rr);                           /* quad xor3 */ \
    float A  = qodd ? b1 : rr,  B  = qodd ? b3 : b2; \
    float A2 = qodd ? rr : b1,  B2 = qodd ? b2 : b3; \
    float i_ = qhi ? B  : A,    g_ = qhi ? A  : B; \
    float f_ = qhi ? B2 : A2,   o_ = qhi ? A2 : B2; \
    float o2 = o_ + o_; \
    c = fmaf(f_, c, i_ * g_);                            /* scaled cell */ \
    float e2 = fexp2f(c); \
    float rv = frcpf(e2 + 1.0f); \
    hmy = fmaf(-o2, rv, o_);                             /* o * tanh(c) */ \
    if (q == 0) hbuf[WB][unit] = __builtin_bit_cast(short, (_Float16)hmy); \
    asm volatile("s_waitcnt lgkmcnt(0)" ::: "memory"); \
    __builtin_amdgcn_s_barrier(); \
    asm volatile("" ::: "memory"); \
}

    for (int t = 0; t < TSEQ; t += 4) {
        STEP(hp0, 1, gx0, tk0, t)
        STEP(hp1, 0, gx1, tk1, t + 1)
        STEP(hp0, 1, gx2, tk2, t + 2)
        STEP(hp1, 0, gx3, tk3, t + 3)
    }
#undef STEP
#undef DOTG

    // epilogue: final h (replicated per quad) -> BN -> FC
    if (q == 0) hfin[unit] = hmy;
    __syncthreads();
    if (tid < HIDDEN) {
        float hb = (hfin[tid] - bn_mean[tid]) * rsqrtf(bn_var[tid] + 1e-5f)
                   * bn_gamma[tid] + bn_beta[tid];
        hb_s[tid] = hb;
    }
    __syncthreads();
    if (tid < NUM_OUT) {
        float s0 = fc_b[tid], s1 = 0.f, s2 = 0.f, s3 = 0.f;
        #pragma unroll
        for (int k = 0; k < HIDDEN; k += 4) {
            s0 = fmaf(hb_s[k + 0], fc_w[tid * HIDDEN + k + 0], s0);
            s1 = fmaf(hb_s[k + 1], fc_w[tid * HIDDEN + k + 1], s1);
            s2 = fmaf(hb_s[k + 2], fc_w[tid * HIDDEN + k + 2], s2);
            s3 = fmaf(hb_s[k + 3], fc_w[tid * HIDDEN + k + 3], s3);
        }
        out[b * NUM_OUT + tid] = (s0 + s1) + (s2 + s3);
    }
}

// ---------------------------------------------------------------------------
extern "C" void kernel_launch(void* const* d_in, const int* in_sizes, int n_in,
                              void* d_out, int out_size, void* d_ws, size_t ws_size,
                              hipStream_t stream) {
    const int*   x        = (const int*)d_in[0];
    // d_in[1] = seq_lengths: unused by the reference computation
    const float* emb      = (const float*)d_in[2];
    const float* W_ih     = (const float*)d_in[3];
    const float* W_hh     = (const float*)d_in[4];
    const float* b_ih     = (const float*)d_in[5];
    const float* b_hh     = (const float*)d_in[6];
    const float* bn_gamma = (const float*)d_in[7];
    const float* bn_beta  = (const float*)d_in[8];
    const float* bn_mean  = (const float*)d_in[9];
    const float* bn_var   = (const float*)d_in[10];
    const float* fc_w     = (const float*)d_in[11];
    const float* fc_b     = (const float*)d_in[12];

    float* proj = (float*)d_ws;  // VOCAB * 256 * 4 B = 51.2 MB

    wcvt_kernel<<<G4 * EMBED / (256 * 4), 256, 0, stream>>>(W_ih);
    proj_mfma<<<(VOCAB + 63) / 64, 256, 0, stream>>>(emb, b_ih, b_hh, proj);

    lstm_scan<<<BATCH, 256, 0, stream>>>(x, proj, W_hh,
                                         bn_gamma, bn_beta, bn_mean, bn_var,
                                         fc_w, fc_b, (float*)d_out);
}